// Round 1
// baseline (50.390 us; speedup 1.0000x reference)
//
#include <hip/hip_runtime.h>
#include <stdint.h>

typedef __attribute__((ext_vector_type(4))) float  f32x4;
typedef __attribute__((ext_vector_type(8))) __bf16 bf16x8;

#define NB   32
#define CC   512
#define DD   512
#define HW   1024
#define BM   128
#define BN   128
#define BK   32

static __device__ __forceinline__ uint32_t f2bf(float x) {
    uint32_t u = __float_as_uint(x);
    return (u + 0x7FFFu + ((u >> 16) & 1u)) >> 16;   // RNE bf16
}

// ---------------- softmax over last dim of atts -> bf16 W in ws -------------
// one wave per row (n,c); 512 cols; 8 floats per lane (two float4, coalesced)
__global__ __launch_bounds__(256) void softmax_rows(
        const float* __restrict__ atts, unsigned short* __restrict__ W) {
    const int tid  = threadIdx.x;
    const int wid  = tid >> 6;
    const int lane = tid & 63;
    const int row  = blockIdx.x * 4 + wid;          // 0..16383
    const float* a = atts + (size_t)row * DD;

    float4 v0 = *(const float4*)(a + lane * 4);
    float4 v1 = *(const float4*)(a + 256 + lane * 4);
    float e[8] = {v0.x, v0.y, v0.z, v0.w, v1.x, v1.y, v1.z, v1.w};

    float m = e[0];
    #pragma unroll
    for (int j = 1; j < 8; ++j) m = fmaxf(m, e[j]);
    #pragma unroll
    for (int s = 1; s < 64; s <<= 1) m = fmaxf(m, __shfl_xor(m, s, 64));

    float sum = 0.f;
    #pragma unroll
    for (int j = 0; j < 8; ++j) { e[j] = __expf(e[j] - m); sum += e[j]; }
    #pragma unroll
    for (int s = 1; s < 64; s <<= 1) sum += __shfl_xor(sum, s, 64);
    const float inv = 1.0f / sum;

    uint32_t p[4];
    #pragma unroll
    for (int j = 0; j < 4; ++j)
        p[j] = f2bf(e[2*j] * inv) | (f2bf(e[2*j+1] * inv) << 16);

    unsigned short* wr = W + (size_t)row * DD;
    uint2 s0 = {p[0], p[1]};
    uint2 s1 = {p[2], p[3]};
    *(uint2*)(wr + lane * 4)       = s0;            // 8B/lane, coalesced
    *(uint2*)(wr + 256 + lane * 4) = s1;
}

// ---------------- batched GEMM: out[n] = W[n] (512x512) x images[n] (512x1024)
// 128x128 tile, BK=32, 4 waves (2x2 of 64x64), mfma 16x16x32 bf16
__global__ __launch_bounds__(256) void gemm_kernel(
        const float* __restrict__ images, const unsigned short* __restrict__ W,
        float* __restrict__ out) {
    __shared__ unsigned short lA[BM * BK];       // [row][k]  linear, 8KB
    __shared__ unsigned short lB[4 * BN * 8];    // [kg][n][8] conflict-free, 8KB

    // XCD-aware swizzle: all 32 tiles of batch n land on XCD n%8
    const int b  = blockIdx.x;       // 0..1023
    const int g  = b & 7;
    const int i  = b >> 3;           // 0..127
    const int n  = (i >> 5) * 8 + g; // batch 0..31
    const int tl = i & 31;
    const int mb = tl >> 3;          // 0..3
    const int nb = tl & 7;           // 0..7

    const float*          gI = images + (size_t)n * DD * HW + nb * BN;
    const unsigned short* gW = W + (size_t)n * CC * DD + (size_t)(mb * BM) * DD;
    float*                gO = out + (size_t)n * CC * HW + (size_t)(mb * BM) * HW + nb * BN;

    const int tid  = threadIdx.x;
    const int lane = tid & 63;
    const int wid  = tid >> 6;
    const int wm   = wid >> 1;       // 0..1
    const int wn   = wid & 1;        // 0..1

    // B staging decode: wave-uniform kg, float2 along hw
    const int bkg = tid >> 6;        // 0..3
    const int bn  = (tid & 63) * 2;  // 0..126

    const int r15 = lane & 15;
    const int kgl = lane >> 4;

    f32x4 acc[4][4] = {};

    for (int ks = 0; ks < DD / BK; ++ks) {
        __syncthreads();
        // ---- A: W tile 128x32 bf16 via global_load_lds (2 x 4KB) ----
        #pragma unroll
        for (int p = 0; p < 2; ++p) {
            const int idx = p * 256 + tid;
            const int row = idx >> 2;
            const int kg  = idx & 3;
            const unsigned short* src = gW + (size_t)row * DD + ks * BK + kg * 8;
            __builtin_amdgcn_global_load_lds(
                (const __attribute__((address_space(1))) void*)src,
                (__attribute__((address_space(3))) void*)&lA[idx * 8],
                16, 0, 0);
        }
        // ---- B: images tile 32x128 fp32 -> bf16, LDS [kg][n][8] ----
        const float* srcB = gI + (size_t)(ks * BK + bkg * 8) * HW + bn;
        float x0[8], x1[8];
        #pragma unroll
        for (int j = 0; j < 8; ++j) {
            float2 v = *(const float2*)(srcB + (size_t)j * HW);
            x0[j] = v.x; x1[j] = v.y;
        }
        uint32_t q0[4], q1[4];
        #pragma unroll
        for (int j = 0; j < 4; ++j) {
            q0[j] = f2bf(x0[2*j]) | (f2bf(x0[2*j+1]) << 16);
            q1[j] = f2bf(x1[2*j]) | (f2bf(x1[2*j+1]) << 16);
        }
        uint4 w0 = {q0[0], q0[1], q0[2], q0[3]};
        uint4 w1 = {q1[0], q1[1], q1[2], q1[3]};
        *(uint4*)&lB[bkg * (BN * 8) + bn * 8]       = w0;
        *(uint4*)&lB[bkg * (BN * 8) + (bn + 1) * 8] = w1;

        __syncthreads();

        // ---- fragments + MFMA ----
        bf16x8 af[4], bv[4];
        #pragma unroll
        for (int m = 0; m < 4; ++m)
            af[m] = *(const bf16x8*)&lA[(wm * 64 + m * 16 + r15) * BK + kgl * 8];
        #pragma unroll
        for (int nf = 0; nf < 4; ++nf)
            bv[nf] = *(const bf16x8*)&lB[kgl * (BN * 8) + (wn * 64 + nf * 16 + r15) * 8];
        #pragma unroll
        for (int m = 0; m < 4; ++m)
            #pragma unroll
            for (int nf = 0; nf < 4; ++nf)
                acc[m][nf] = __builtin_amdgcn_mfma_f32_16x16x32_bf16(
                    af[m], bv[nf], acc[m][nf], 0, 0, 0);
    }

    // ---- epilogue: C/D layout col=lane&15, row=(lane>>4)*4+r ----
    #pragma unroll
    for (int m = 0; m < 4; ++m)
        #pragma unroll
        for (int nf = 0; nf < 4; ++nf)
            #pragma unroll
            for (int r = 0; r < 4; ++r) {
                const int row = wm * 64 + m * 16 + kgl * 4 + r;
                const int col = wn * 64 + nf * 16 + r15;
                gO[(size_t)row * HW + col] = acc[m][nf][r];
            }
}

extern "C" void kernel_launch(void* const* d_in, const int* in_sizes, int n_in,
                              void* d_out, int out_size, void* d_ws, size_t ws_size,
                              hipStream_t stream) {
    const float* images = (const float*)d_in[0];
    const float* atts   = (const float*)d_in[1];
    float*       out    = (float*)d_out;
    unsigned short* Wbf = (unsigned short*)d_ws;   // 32*512*512*2 = 16.8 MB

    softmax_rows<<<dim3(NB * CC / 4), dim3(256), 0, stream>>>(atts, Wbf);
    gemm_kernel<<<dim3(NB * (CC / BM) * (HW / BN)), dim3(256), 0, stream>>>(images, Wbf, out);
}